// Round 9
// baseline (116.112 us; speedup 1.0000x reference)
//
#include <hip/hip_runtime.h>

constexpr int N_NODES = 50000;
constexpr int N_EDGES = 800000;
constexpr int D = 64;

constexpr int NREG = 512;    // destination regions (one gin block each; 2 blocks/CU)
constexpr int RSZ = 98;      // nodes per region (512*98 = 50176 >= 50000)
constexpr int EPB = 4096;    // edges per prep block
constexpr int NBINB = 196;   // ceil(800000/4096)
constexpr int CELLCAP = 48;  // per-(region,block) cell cap; mean 8, >12 sigma margin
constexpr int RECAP = 2048;  // per-region edge cap; mean 1562, sigma ~40 (12 sigma)

// Workspace layout:
//   cnt2 [NREG*NBINB] ints          at int 0        (400 KB)
//   rbuf [NREG*NBINB*CELLCAP] ints  at int 100352   (19.3 MB, 192B cells, 16B-aligned)
//   hb   [N_NODES*D] ushorts        at byte 19668992 (6.4 MB)
constexpr int WS_CNT2 = 0;
constexpr int WS_RBUF = NREG * NBINB;  // 100352
constexpr size_t WS_HB_BYTE = (size_t)(WS_RBUF + NREG * NBINB * CELLCAP) * 4;

using vfloat4 = __attribute__((ext_vector_type(4))) float;  // native vec for NT ops

__device__ __forceinline__ ushort to_bf16(float x) {
  unsigned u = __float_as_uint(x);
  u += 0x7FFF + ((u >> 16) & 1);  // RNE
  return (ushort)(u >> 16);
}
__device__ __forceinline__ float from_bf16(ushort h) {
  return __uint_as_float((unsigned)h << 16);
}

// Fused: feat->bf16 conversion slice + edge binning into per-(region,block)
// cells. LDS cursor per region only; gin sorts per region.
__global__ __launch_bounds__(1024) void prep_kernel(
    const float4* __restrict__ feat4, const int* __restrict__ src,
    const int* __restrict__ dst, ushort* __restrict__ hb,
    int* __restrict__ cnt2, unsigned* __restrict__ rbuf) {
  __shared__ int cur[NREG];
  int tid = threadIdx.x, blk = blockIdx.x;
  if (tid < NREG) cur[tid] = 0;

  // Start edge loads early; latency hidden behind the bf16 conversion.
  int e0 = blk * EPB + tid * 4;
  bool valid = (e0 + 4 <= N_EDGES);  // N_EDGES % 4 == 0
  int4 d4 = {0, 0, 0, 0}, s4 = {0, 0, 0, 0};
  if (valid) {
    d4 = *reinterpret_cast<const int4*>(dst + e0);
    s4 = *reinterpret_cast<const int4*>(src + e0);
  }

  // bf16 conversion: 4096 float4 per block (196*4096 >= 800000 float4s).
  int cb = blk * 4096 + tid;
#pragma unroll
  for (int k = 0; k < 4; ++k) {
    int t = cb + k * 1024;
    if (t < N_NODES * D / 4) {
      float4 f = feat4[t];
      ushort4 h;
      h.x = to_bf16(f.x); h.y = to_bf16(f.y);
      h.z = to_bf16(f.z); h.w = to_bf16(f.w);
      *reinterpret_cast<ushort4*>(hb + t * 4) = h;
    }
  }
  __syncthreads();

  if (valid) {
    const int dd[4] = {d4.x, d4.y, d4.z, d4.w};
    const int ss[4] = {s4.x, s4.y, s4.z, s4.w};
#pragma unroll
    for (int k = 0; k < 4; ++k) {
      int r = dd[k] / RSZ;  // magic-mul
      unsigned pk = ((unsigned)(dd[k] - r * RSZ) << 16) | (unsigned)ss[k];
      int p = atomicAdd(&cur[r], 1);
      if (p < CELLCAP)
        rbuf[(size_t)(r * NBINB + blk) * CELLCAP + p] = pk;
    }
  }
  __syncthreads();
  // 2 threads per region write the cell count + nothing else (data already out).
  if (tid < NREG) {
    int c = cur[tid];
    cnt2[tid * NBINB + blk] = (c > CELLCAP) ? CELLCAP : c;
  }
}

// One block per region (512 blocks x 512 threads = 2 blocks/CU): gather the
// region's edges from cells into LDS, counting-sort by local node, then
// per-node bf16 gather + residual + Linear via width-16 shuffles.
__global__ __launch_bounds__(512) void gin_kernel(
    const float* __restrict__ feat, const ushort* __restrict__ hb,
    const float* __restrict__ W, const float* __restrict__ b,
    const float* __restrict__ eps, const int* __restrict__ cnt2,
    const unsigned* __restrict__ rbuf, float* __restrict__ out) {
  __shared__ float Wt[D * D];       // 16 KB: Wt[i*64+o] = W[o*64+i]
  __shared__ unsigned ebuf[RECAP];  // 8 KB: unsorted region edges
  __shared__ ushort sorted[RECAP];  // 4 KB: src indices sorted by node
  __shared__ int cellstart[NBINB + 1];
  __shared__ int hist[RSZ], nstart[RSZ + 1], cursor[RSZ];
  __shared__ int scan_tmp[256];

  int tid = threadIdx.x, r = blockIdx.x;
  for (int q = tid; q < D * D; q += 512) Wt[q] = W[((q & 63) << 6) + (q >> 6)];
  if (tid < RSZ) hist[tid] = 0;

  // Scan cell counts (contiguous 196-int read; cnt2 is region-major).
  int c = (tid < NBINB) ? cnt2[r * NBINB + tid] : 0;
  if (tid < 256) scan_tmp[tid] = c;
  __syncthreads();
  for (int ofs = 1; ofs < 256; ofs <<= 1) {
    int v = 0;
    if (tid < 256 && tid >= ofs) v = scan_tmp[tid - ofs];
    __syncthreads();
    if (tid < 256) scan_tmp[tid] += v;
    __syncthreads();
  }
  if (tid < NBINB) cellstart[tid] = scan_tmp[tid] - c;
  if (tid == NBINB - 1) cellstart[NBINB] = scan_tmp[tid];
  __syncthreads();
  int T = cellstart[NBINB];
  if (T > RECAP) T = RECAP;  // statistically impossible

  // Concatenate cells into ebuf: 4 threads per cell, uint4 loads, 2 passes.
  for (int cell = tid >> 2; cell < NBINB; cell += 128) {
    int sub = tid & 3;
    int cs = cellstart[cell];
    int cc = cellstart[cell + 1] - cs;
    const unsigned* cp = rbuf + (size_t)(r * NBINB + cell) * CELLCAP;
    for (int i = sub * 4; i < cc; i += 16) {
      uint4 v = *reinterpret_cast<const uint4*>(cp + i);  // 16B-aligned
      if (cs + i + 0 < T && i + 0 < cc) ebuf[cs + i + 0] = v.x;
      if (cs + i + 1 < T && i + 1 < cc) ebuf[cs + i + 1] = v.y;
      if (cs + i + 2 < T && i + 2 < cc) ebuf[cs + i + 2] = v.z;
      if (cs + i + 3 < T && i + 3 < cc) ebuf[cs + i + 3] = v.w;
    }
  }
  __syncthreads();

  // Histogram by local node, 128-wide scan (RSZ=98), scatter -> sorted.
  for (int e = tid; e < T; e += 512) atomicAdd(&hist[ebuf[e] >> 16], 1);
  __syncthreads();
  if (tid < 128) scan_tmp[tid] = (tid < RSZ) ? hist[tid] : 0;
  __syncthreads();
  for (int ofs = 1; ofs < 128; ofs <<= 1) {
    int v = 0;
    if (tid < 128 && tid >= ofs) v = scan_tmp[tid - ofs];
    __syncthreads();
    if (tid < 128) scan_tmp[tid] += v;
    __syncthreads();
  }
  if (tid < RSZ) {
    int ex = scan_tmp[tid] - hist[tid];
    nstart[tid] = ex;
    cursor[tid] = ex;
  }
  if (tid == RSZ - 1) nstart[RSZ] = scan_tmp[tid];
  __syncthreads();
  for (int e = tid; e < T; e += 512) {
    unsigned pk = ebuf[e];
    int p = atomicAdd(&cursor[pk >> 16], 1);
    sorted[p] = (ushort)(pk & 0xFFFFu);
  }
  __syncthreads();

  // Per-node gather + residual + matvec. 32 groups x 16 lanes.
  int g = tid >> 4, j4 = (tid & 15) << 2;
  float s = 1.0f + eps[0];

  for (int n = g; n < RSZ; n += 32) {
    int node = r * RSZ + n;
    if (node >= N_NODES) continue;  // group-uniform

    // Nontemporal: don't let the fp32 feat stream evict hb from L2.
    vfloat4 fin = __builtin_nontemporal_load(
        reinterpret_cast<const vfloat4*>(feat + (node << 6) + j4));
    float4 acc;
    acc.x = fin.x * s; acc.y = fin.y * s; acc.z = fin.z * s; acc.w = fin.w * s;

    int e = nstart[n], e1 = nstart[n + 1];
    for (; e + 8 <= e1; e += 8) {
      int i0 = sorted[e + 0], i1 = sorted[e + 1], i2 = sorted[e + 2], i3 = sorted[e + 3];
      int i4_ = sorted[e + 4], i5 = sorted[e + 5], i6 = sorted[e + 6], i7 = sorted[e + 7];
      ushort4 h0 = *reinterpret_cast<const ushort4*>(hb + (i0 << 6) + j4);
      ushort4 h1 = *reinterpret_cast<const ushort4*>(hb + (i1 << 6) + j4);
      ushort4 h2 = *reinterpret_cast<const ushort4*>(hb + (i2 << 6) + j4);
      ushort4 h3 = *reinterpret_cast<const ushort4*>(hb + (i3 << 6) + j4);
      ushort4 h4 = *reinterpret_cast<const ushort4*>(hb + (i4_ << 6) + j4);
      ushort4 h5 = *reinterpret_cast<const ushort4*>(hb + (i5 << 6) + j4);
      ushort4 h6 = *reinterpret_cast<const ushort4*>(hb + (i6 << 6) + j4);
      ushort4 h7 = *reinterpret_cast<const ushort4*>(hb + (i7 << 6) + j4);
      acc.x += (from_bf16(h0.x) + from_bf16(h1.x)) + (from_bf16(h2.x) + from_bf16(h3.x))
             + (from_bf16(h4.x) + from_bf16(h5.x)) + (from_bf16(h6.x) + from_bf16(h7.x));
      acc.y += (from_bf16(h0.y) + from_bf16(h1.y)) + (from_bf16(h2.y) + from_bf16(h3.y))
             + (from_bf16(h4.y) + from_bf16(h5.y)) + (from_bf16(h6.y) + from_bf16(h7.y));
      acc.z += (from_bf16(h0.z) + from_bf16(h1.z)) + (from_bf16(h2.z) + from_bf16(h3.z))
             + (from_bf16(h4.z) + from_bf16(h5.z)) + (from_bf16(h6.z) + from_bf16(h7.z));
      acc.w += (from_bf16(h0.w) + from_bf16(h1.w)) + (from_bf16(h2.w) + from_bf16(h3.w))
             + (from_bf16(h4.w) + from_bf16(h5.w)) + (from_bf16(h6.w) + from_bf16(h7.w));
    }
    for (; e < e1; ++e) {
      int sn = sorted[e];
      ushort4 h = *reinterpret_cast<const ushort4*>(hb + (sn << 6) + j4);
      acc.x += from_bf16(h.x); acc.y += from_bf16(h.y);
      acc.z += from_bf16(h.z); acc.w += from_bf16(h.w);
    }

    float4 res = *reinterpret_cast<const float4*>(b + j4);
#pragma unroll
    for (int i4 = 0; i4 < 16; ++i4) {
      float rx = __shfl(acc.x, i4, 16);
      float ry = __shfl(acc.y, i4, 16);
      float rz = __shfl(acc.z, i4, 16);
      float rw = __shfl(acc.w, i4, 16);
      const float4 w0 = *reinterpret_cast<const float4*>(Wt + ((i4 << 2) + 0) * D + j4);
      const float4 w1 = *reinterpret_cast<const float4*>(Wt + ((i4 << 2) + 1) * D + j4);
      const float4 w2 = *reinterpret_cast<const float4*>(Wt + ((i4 << 2) + 2) * D + j4);
      const float4 w3 = *reinterpret_cast<const float4*>(Wt + ((i4 << 2) + 3) * D + j4);
      res.x += rx * w0.x + ry * w1.x + rz * w2.x + rw * w3.x;
      res.y += rx * w0.y + ry * w1.y + rz * w2.y + rw * w3.y;
      res.z += rx * w0.z + ry * w1.z + rz * w2.z + rw * w3.z;
      res.w += rx * w0.w + ry * w1.w + rz * w2.w + rw * w3.w;
    }
    vfloat4 vres;
    vres.x = res.x; vres.y = res.y; vres.z = res.z; vres.w = res.w;
    __builtin_nontemporal_store(
        vres, reinterpret_cast<vfloat4*>(out + (node << 6) + j4));
  }
}

extern "C" void kernel_launch(void* const* d_in, const int* in_sizes, int n_in,
                              void* d_out, int out_size, void* d_ws, size_t ws_size,
                              hipStream_t stream) {
  const float* feat = (const float*)d_in[0];
  const float* W    = (const float*)d_in[1];
  const float* b    = (const float*)d_in[2];
  const float* eps  = (const float*)d_in[3];
  const int*   src  = (const int*)d_in[4];
  const int*   dst  = (const int*)d_in[5];
  float* out = (float*)d_out;

  int* ws = (int*)d_ws;
  int* cnt2      = ws + WS_CNT2;
  unsigned* rbuf = (unsigned*)(ws + WS_RBUF);
  ushort* hb     = (ushort*)((char*)d_ws + WS_HB_BYTE);

  hipLaunchKernelGGL(prep_kernel, dim3(NBINB), dim3(1024), 0, stream,
                     (const float4*)feat, src, dst, hb, cnt2, rbuf);
  hipLaunchKernelGGL(gin_kernel, dim3(NREG), dim3(512), 0, stream,
                     feat, hb, W, b, eps, cnt2, rbuf, out);
}